// Round 12
// baseline (95.357 us; speedup 1.0000x reference)
//
#include <hip/hip_runtime.h>

#define N_NODES 50000
#define E_EDGES 800000
#define IN_DIM  128
#define OUT_DIM 64
#define NEG_SLOPE 0.01f
#define LDAP 136                            // padded bf16 row stride

#define BUCKETS 196                         // ceil(N/256): bucket = dst>>8
#define NBLK    196                         // sort blocks
#define CHUNK   4096                        // edges per sort block
#define P2CAP   6144
#define GB      ((N_NODES + 63) / 64)       // 782 gemm blocks
#define A4B     ((N_NODES * 16 + 255) / 256)// 3125 a4 blocks
#define EB      ((E_EDGES + 255) / 256)     // 3125 edge blocks

typedef __attribute__((ext_vector_type(8))) short bf16x8;
typedef __attribute__((ext_vector_type(4))) float f32x4;

__device__ __forceinline__ ushort f2bf(float x) {
    unsigned u = __float_as_uint(x);
    return (ushort)((u + 0x7FFFu + ((u >> 16) & 1u)) >> 16);
}
__device__ __forceinline__ float bf2f(ushort u) {
    return __uint_as_float(((unsigned)u) << 16);
}

// ============================================================
// k1: blocks [0,GB) = MFMA gemm (inline probe + inline VALU fallback);
//     blocks [GB, GB+NBLK) = sort_hist.   (frozen r10 body)
// ============================================================
__global__ __launch_bounds__(256) void k1_gemm_hist(
    const float* __restrict__ h, const float* __restrict__ Wf,
    const float* __restrict__ Wfr, const int* __restrict__ dst,
    ushort* __restrict__ z, ushort* __restrict__ zr, int* __restrict__ counts)
{
    __shared__ ushort smem[3 * 64 * LDAP];
    const int t = threadIdx.x;

    if (blockIdx.x >= GB) {
        int* bh = (int*)smem;
        const int b = blockIdx.x - GB;
        for (int i = t; i < BUCKETS; i += 256) bh[i] = 0;
        __syncthreads();
        const int base = b * CHUNK;
        const int end = (base + CHUNK < E_EDGES) ? base + CHUNK : E_EDGES;
        for (int i = base + t; i < end; i += 256)
            atomicAdd(&bh[dst[i] >> 8], 1);
        __syncthreads();
        for (int i = t; i < BUCKETS; i += 256)
            counts[i * NBLK + b] = bh[i];
        return;
    }

    ushort* hs  = smem;
    ushort* wfs = smem + 64 * LDAP;
    ushort* wrs = smem + 2 * 64 * LDAP;

    const int nb0 = blockIdx.x * 64;
    const int lane = t & 63;
    const int lr   = lane & 15;
    const int lq   = lane >> 4;

    int flagv;
    {
        bf16x8 af = {0,0,0,0,0,0,0,0};
        bf16x8 bf = {0,0,0,0,0,0,0,0};
        if (lane < 16) {
            af[0] = (short)f2bf((float)(1 + lane));
            bf[0] = (short)f2bf((float)((1 + lane) * (1 + lane)));
        }
        f32x4 pacc = {0.f, 0.f, 0.f, 0.f};
        pacc = __builtin_amdgcn_mfma_f32_16x16x32_bf16(af, bf, pacc, 0, 0, 0);
        bool ok0 = true, ok1 = true;
        #pragma unroll
        for (int r = 0; r < 4; ++r) {
            float e0 = (float)((1 + lq * 4 + r) * (1 + lr) * (1 + lr));
            float e1 = (float)((1 + lr) * (1 + lq * 4 + r) * (1 + lq * 4 + r));
            ok0 = ok0 && (pacc[r] == e0);
            ok1 = ok1 && (pacc[r] == e1);
        }
        flagv = __all(ok0 ? 1 : 0) ? 0 : (__all(ok1 ? 1 : 0) ? 1 : 4);
    }

    #pragma unroll
    for (int i = 0; i < 8; ++i) {
        int elem = i * 1024 + t * 4;
        int row = elem >> 7, col = elem & 127;
        int hn = nb0 + row; if (hn >= N_NODES) hn = N_NODES - 1;
        float4 hv = *(const float4*)&h  [(size_t)hn  * IN_DIM + col];
        float4 fv = *(const float4*)&Wf [(size_t)row * IN_DIM + col];
        float4 rv = *(const float4*)&Wfr[(size_t)row * IN_DIM + col];
        ushort4 hu = { f2bf(hv.x), f2bf(hv.y), f2bf(hv.z), f2bf(hv.w) };
        ushort4 fu = { f2bf(fv.x), f2bf(fv.y), f2bf(fv.z), f2bf(fv.w) };
        ushort4 ru = { f2bf(rv.x), f2bf(rv.y), f2bf(rv.z), f2bf(rv.w) };
        *(ushort4*)&hs [row * LDAP + col] = hu;
        *(ushort4*)&wfs[row * LDAP + col] = fu;
        *(ushort4*)&wrs[row * LDAP + col] = ru;
    }
    __syncthreads();

    if (flagv >= 2) {
        const int og = t & 15;
        const int ng = t >> 4;
        #pragma unroll
        for (int i = 0; i < 4; ++i) {
            const int nrow = ng * 4 + i;
            const int node = nb0 + nrow;
            if (node >= N_NODES) continue;
            float acf[4] = {0.f, 0.f, 0.f, 0.f};
            float acr[4] = {0.f, 0.f, 0.f, 0.f};
            for (int k = 0; k < IN_DIM; ++k) {
                float hv = bf2f(hs[nrow * LDAP + k]);
                #pragma unroll
                for (int jj = 0; jj < 4; ++jj) {
                    acf[jj] = fmaf(hv, bf2f(wfs[(og * 4 + jj) * LDAP + k]), acf[jj]);
                    acr[jj] = fmaf(hv, bf2f(wrs[(og * 4 + jj) * LDAP + k]), acr[jj]);
                }
            }
            #pragma unroll
            for (int jj = 0; jj < 4; ++jj) {
                z [(size_t)node * OUT_DIM + og * 4 + jj] = f2bf(acf[jj]);
                zr[(size_t)node * OUT_DIM + og * 4 + jj] = f2bf(acr[jj]);
            }
        }
        return;
    }

    const int w = t >> 6;

    f32x4 accf[4], accr[4];
    #pragma unroll
    for (int cb = 0; cb < 4; ++cb) {
        accf[cb] = (f32x4){0.f, 0.f, 0.f, 0.f};
        accr[cb] = (f32x4){0.f, 0.f, 0.f, 0.f};
    }

    #pragma unroll
    for (int kc = 0; kc < 4; ++kc) {
        const int koff = kc * 32 + lq * 8;
        bf16x8 af = *(bf16x8*)&hs[(w * 16 + lr) * LDAP + koff];
        #pragma unroll
        for (int cb = 0; cb < 4; ++cb) {
            bf16x8 bfr = *(bf16x8*)&wfs[(cb * 16 + lr) * LDAP + koff];
            bf16x8 brr = *(bf16x8*)&wrs[(cb * 16 + lr) * LDAP + koff];
            accf[cb] = __builtin_amdgcn_mfma_f32_16x16x32_bf16(af, bfr, accf[cb], 0, 0, 0);
            accr[cb] = __builtin_amdgcn_mfma_f32_16x16x32_bf16(af, brr, accr[cb], 0, 0, 0);
        }
    }

    #pragma unroll
    for (int reg = 0; reg < 4; ++reg) {
        const int aIdx = (flagv == 0) ? (lq * 4 + reg) : lr;
        const int bIdx = (flagv == 0) ? lr : (lq * 4 + reg);
        const int node = nb0 + w * 16 + aIdx;
        if (node < N_NODES) {
            #pragma unroll
            for (int cb = 0; cb < 4; ++cb) {
                z [(size_t)node * OUT_DIM + cb * 16 + bIdx] = f2bf(accf[cb][reg]);
                zr[(size_t)node * OUT_DIM + cb * 16 + bIdx] = f2bf(accr[cb][reg]);
            }
        }
    }
}

// ============================================================
// k2: blocks [0,A4B) = a4; blocks [A4B, A4B+BUCKETS) = sort_scanA. (frozen)
// ============================================================
__global__ __launch_bounds__(256) void k2_a4_scanA(
    const ushort* __restrict__ z, const ushort* __restrict__ zr,
    const float* __restrict__ Wa, float4* __restrict__ a4,
    const int* __restrict__ counts, int* __restrict__ scanw,
    int* __restrict__ btot)
{
    __shared__ int tmp[256];
    const int t = threadIdx.x;

    if (blockIdx.x >= A4B) {
        const int j = blockIdx.x - A4B;
        int v = (t < NBLK) ? counts[j * NBLK + t] : 0;
        tmp[t] = v; __syncthreads();
        #pragma unroll
        for (int off = 1; off < 256; off <<= 1) {
            int u = (t >= off) ? tmp[t - off] : 0;
            __syncthreads();
            tmp[t] += u;
            __syncthreads();
        }
        if (t < NBLK) scanw[j * NBLK + t] = tmp[t] - v;
        if (t == 255) btot[j] = tmp[t];
        return;
    }

    int gid = blockIdx.x * 256 + t;
    int node = gid >> 4;
    int lr = t & 15;
    if (node >= N_NODES) return;
    ushort4 zv = *(const ushort4*)&z [(size_t)node * OUT_DIM + lr * 4];
    ushort4 rv = *(const ushort4*)&zr[(size_t)node * OUT_DIM + lr * 4];
    float4 ws4 = *(const float4*)&Wa[lr * 4];
    float4 wd4 = *(const float4*)&Wa[64 + lr * 4];
    float pSf = bf2f(zv.x)*ws4.x + bf2f(zv.y)*ws4.y + bf2f(zv.z)*ws4.z + bf2f(zv.w)*ws4.w;
    float pDf = bf2f(zv.x)*wd4.x + bf2f(zv.y)*wd4.y + bf2f(zv.z)*wd4.z + bf2f(zv.w)*wd4.w;
    float pSr = bf2f(rv.x)*ws4.x + bf2f(rv.y)*ws4.y + bf2f(rv.z)*ws4.z + bf2f(rv.w)*ws4.w;
    float pDr = bf2f(rv.x)*wd4.x + bf2f(rv.y)*wd4.y + bf2f(rv.z)*wd4.z + bf2f(rv.w)*wd4.w;
    #pragma unroll
    for (int mm = 1; mm < 16; mm <<= 1) {
        pSf += __shfl_xor(pSf, mm, 64);
        pDf += __shfl_xor(pDf, mm, 64);
        pSr += __shfl_xor(pSr, mm, 64);
        pDr += __shfl_xor(pDr, mm, 64);
    }
    if (lr == 0) a4[node] = make_float4(pSf, pDf, pSr, pDr);
}

// ============================================================
// k2b: edge-parallel w = exp(leaky(logit)) -> wtmp[e] (original order).
// High-TLP context for the random a4 gathers (r11 lesson).
// ============================================================
__global__ __launch_bounds__(256) void k2b_w(
    const int* __restrict__ src, const int* __restrict__ dst,
    const float2* __restrict__ dir, const float4* __restrict__ a4,
    float* __restrict__ wtmp)
{
    int e = blockIdx.x * 256 + threadIdx.x;
    if (e >= E_EDGES) return;
    int s = src[e], d = dst[e];
    bool rev = (dir[e].y != 0.f);
    float4 as = a4[s];
    float4 ad = a4[d];
    float tl = rev ? (as.z + ad.w) : (as.x + ad.y);
    tl = (tl > 0.f) ? tl : NEG_SLOPE * tl;
    wtmp[e] = __expf(tl);                    // no-max softmax: fp32-safe
}

// ============================================================
// k3: scatter (r10 LDS structure) emitting {pe, w_bits} records.
// pe = src(16b) | (dst&255)<<16 | dir<<31 ; w read coalesced from wtmp.
// ============================================================
__global__ __launch_bounds__(256) void k3_scatter(
    const int* __restrict__ src, const int* __restrict__ dst,
    const float2* __restrict__ dir, const int* __restrict__ scanw,
    const int* __restrict__ btot, const float* __restrict__ wtmp,
    int2* __restrict__ tmpbuf)
{
    __shared__ int2 recs[CHUNK];      // {pe, dst}
    __shared__ int bh[BUCKETS];
    __shared__ int sc[256];
    __shared__ int cur[BUCKETS];
    __shared__ int exb[256];

    const int b = blockIdx.x;
    const int t = threadIdx.x;

    {
        int v = (t < BUCKETS) ? btot[t] : 0;
        exb[t] = v; __syncthreads();
        #pragma unroll
        for (int off = 1; off < 256; off <<= 1) {
            int u = (t >= off) ? exb[t - off] : 0;
            __syncthreads();
            exb[t] += u;
            __syncthreads();
        }
        int ex = exb[t] - v;
        __syncthreads();
        exb[t] = ex;
    }

    const int base = b * CHUNK;
    const int end = (base + CHUNK < E_EDGES) ? base + CHUNK : E_EDGES;
    const int cnt = end - base;

    for (int i = t; i < BUCKETS; i += 256) bh[i] = 0;
    __syncthreads();

    for (int i = t; i < cnt; i += 256) {
        int e = base + i;
        int d = dst[e];
        int s = src[e];
        bool rev = (dir[e].y != 0.f);
        int pe = s | ((d & 255) << 16) | (rev ? 0x80000000 : 0);
        recs[i] = make_int2(pe, d);
        atomicAdd(&bh[d >> 8], 1);
    }
    __syncthreads();

    sc[t] = (t < BUCKETS) ? bh[t] : 0;
    __syncthreads();
    #pragma unroll
    for (int off = 1; off < 256; off <<= 1) {
        int v = (t >= off) ? sc[t - off] : 0;
        __syncthreads();
        sc[t] += v;
        __syncthreads();
    }
    if (t < BUCKETS) cur[t] = (t > 0) ? sc[t - 1] : 0;
    __syncthreads();

    for (int i = t; i < cnt; i += 256) {
        int2 r = recs[i];
        int bkt = r.y >> 8;
        int loc = atomicAdd(&cur[bkt], 1);
        int lbase = (bkt > 0) ? sc[bkt - 1] : 0;
        tmpbuf[scanw[bkt * NBLK + b] + exb[bkt] + (loc - lbase)] =
            make_int2(r.x, __float_as_int(wtmp[base + i]));   // coalesced L2-hot
    }
}

// ============================================================
// k4: per-bucket node sort; emits csr2 {pe,w}, start[], inv[]  (r11 proven)
// ============================================================
__global__ __launch_bounds__(256) void k4_pass2(
    const int* __restrict__ btot, const int2* __restrict__ tmpbuf,
    int2* __restrict__ csr2, int* __restrict__ start, float* __restrict__ inv)
{
    __shared__ int nh[256];
    __shared__ int nex[256];
    __shared__ int ncur[256];
    __shared__ int stmp[256];
    __shared__ float wsum[256];
    __shared__ int2 recs[P2CAP];

    const int j = blockIdx.x;
    const int t = threadIdx.x;

    int v = (t < BUCKETS) ? btot[t] : 0;
    stmp[t] = v; __syncthreads();
    #pragma unroll
    for (int off = 1; off < 256; off <<= 1) {
        int u = (t >= off) ? stmp[t - off] : 0;
        __syncthreads();
        stmp[t] += u;
        __syncthreads();
    }
    const int gbeg = stmp[j] - btot[j];
    const int cnt  = btot[j];
    const bool fits = (cnt <= P2CAP);

    nh[t] = 0;
    wsum[t] = 0.f;
    __syncthreads();

    for (int i = t; i < cnt; i += 256) {
        int2 r = tmpbuf[gbeg + i];
        if (fits) recs[i] = r;
        int lid = (r.x >> 16) & 255;
        atomicAdd(&nh[lid], 1);
        atomicAdd(&wsum[lid], __int_as_float(r.y));
    }
    __syncthreads();

    nex[t] = nh[t];
    __syncthreads();
    #pragma unroll
    for (int off = 1; off < 256; off <<= 1) {
        int u = (t >= off) ? nex[t - off] : 0;
        __syncthreads();
        nex[t] += u;
        __syncthreads();
    }
    int excl = (t > 0) ? nex[t - 1] : 0;
    ncur[t] = excl;
    const int node = j * 256 + t;
    if (node < N_NODES) {
        start[node] = gbeg + excl;
        inv[node] = 1.f / fmaxf(wsum[t], 1e-9f);
    }
    if (j == BUCKETS - 1 && t == 0) start[N_NODES] = E_EDGES;
    __syncthreads();

    for (int i = t; i < cnt; i += 256) {
        int2 r = fits ? recs[i] : tmpbuf[gbeg + i];
        int lid = (r.x >> 16) & 255;
        int loc = atomicAdd(&ncur[lid], 1);
        csr2[gbeg + loc] = r;
    }
}

// ============================================================
// k5: pure weighted gather (r11 proven body)
// ============================================================
__global__ __launch_bounds__(256) void k5_aggregate(
    const int* __restrict__ start, const int2* __restrict__ csr2,
    const float* __restrict__ inv, const ushort* __restrict__ z,
    const ushort* __restrict__ zr, float* __restrict__ out)
{
    int gid = blockIdx.x * 256 + threadIdx.x;
    int node = gid >> 6;
    int lane = threadIdx.x & 63;
    int l = lane & 15;      // channel quad
    int g = lane >> 4;      // edge slot
    if (node >= N_NODES) return;

    const int s0 = start[node];
    const int s1 = start[node + 1];

    float ax = 0.f, ay = 0.f, az = 0.f, aw = 0.f;

    for (int j = s0 + g; j < s1; j += 4) {
        int2 r = csr2[j];
        float wj = __int_as_float(r.y);
        int sd = r.x & 0xFFFF;
        const ushort* __restrict__ row = (r.x < 0) ? zr : z;
        ushort4 v = *(const ushort4*)&row[(size_t)sd * OUT_DIM + l * 4];
        ax = fmaf(wj, bf2f(v.x), ax);
        ay = fmaf(wj, bf2f(v.y), ay);
        az = fmaf(wj, bf2f(v.z), az);
        aw = fmaf(wj, bf2f(v.w), aw);
    }

    ax += __shfl_xor(ax, 16, 64); ax += __shfl_xor(ax, 32, 64);
    ay += __shfl_xor(ay, 16, 64); ay += __shfl_xor(ay, 32, 64);
    az += __shfl_xor(az, 16, 64); az += __shfl_xor(az, 32, 64);
    aw += __shfl_xor(aw, 16, 64); aw += __shfl_xor(aw, 32, 64);

    if (g == 0) {
        float iv = inv[node];
        *(float4*)&out[(size_t)node * OUT_DIM + l * 4] =
            make_float4(ax * iv, ay * iv, az * iv, aw * iv);
    }
}

extern "C" void kernel_launch(void* const* d_in, const int* in_sizes, int n_in,
                              void* d_out, int out_size, void* d_ws, size_t ws_size,
                              hipStream_t stream) {
    const float*  h   = (const float*) d_in[0];
    const float*  Wf  = (const float*) d_in[1];
    const float*  Wfr = (const float*) d_in[2];
    const float*  Wa  = (const float*) d_in[3];
    const float2* dir = (const float2*)d_in[4];
    const int*    src = (const int*)   d_in[5];
    const int*    dst = (const int*)   d_in[6];
    float* out = (float*)d_out;

    // ws (4B words): zb zrb | a4 | counts scanw btot start inv | wtmp | tmp csr2
    ushort*   zb     = (ushort*)d_ws;
    ushort*   zrb    = zb + (size_t)N_NODES * OUT_DIM;
    float4*   a4     = (float4*)(zrb + (size_t)N_NODES * OUT_DIM);
    int*      counts = (int*)(a4 + N_NODES);
    int*      scanw  = counts + 38656;
    int*      btot   = scanw + 38656;
    int*      start  = btot + 256;
    float*    inv    = (float*)(start + 50016);
    float*    wtmp   = inv + 50048;
    int2*     tmp    = (int2*)(wtmp + E_EDGES);
    int2*     csr2   = tmp + E_EDGES;

    k1_gemm_hist <<<GB + NBLK, 256, 0, stream>>>(h, Wf, Wfr, dst, zb, zrb, counts);
    k2_a4_scanA  <<<A4B + BUCKETS, 256, 0, stream>>>(zb, zrb, Wa, a4, counts, scanw, btot);
    k2b_w        <<<EB, 256, 0, stream>>>(src, dst, dir, a4, wtmp);
    k3_scatter   <<<NBLK, 256, 0, stream>>>(src, dst, dir, scanw, btot, wtmp, tmp);
    k4_pass2     <<<BUCKETS, 256, 0, stream>>>(btot, tmp, csr2, start, inv);
    k5_aggregate <<<(N_NODES * 64 + 255) / 256, 256, 0, stream>>>(start, csr2, inv, zb, zrb, out);
}

// Round 13
// 82.207 us; speedup vs baseline: 1.1600x; 1.1600x over previous
//
#include <hip/hip_runtime.h>

#define N_NODES 50000
#define E_EDGES 800000
#define IN_DIM  128
#define OUT_DIM 64
#define NEG_SLOPE 0.01f
#define LDAP 136                            // padded bf16 row stride

#define BUCKETS 196                         // ceil(N/256): bucket = dst>>8
#define NBLK    196                         // sort blocks
#define CHUNK   4096                        // edges per sort block
#define P2CAP   6144
#define GB      ((N_NODES + 63) / 64)       // 782 gemm blocks
#define A4B     ((N_NODES * 16 + 255) / 256)// 3125 a4 blocks

typedef __attribute__((ext_vector_type(8))) short bf16x8;
typedef __attribute__((ext_vector_type(4))) float f32x4;

__device__ __forceinline__ ushort f2bf(float x) {
    unsigned u = __float_as_uint(x);
    return (ushort)((u + 0x7FFFu + ((u >> 16) & 1u)) >> 16);
}
__device__ __forceinline__ float bf2f(ushort u) {
    return __uint_as_float(((unsigned)u) << 16);
}

// ============================================================
// k1: blocks [0,GB) = MFMA gemm (inline probe + inline VALU fallback);
//     blocks [GB, GB+NBLK) = sort_hist.
// ============================================================
__global__ __launch_bounds__(256) void k1_gemm_hist(
    const float* __restrict__ h, const float* __restrict__ Wf,
    const float* __restrict__ Wfr, const int* __restrict__ dst,
    ushort* __restrict__ z, ushort* __restrict__ zr, int* __restrict__ counts)
{
    __shared__ ushort smem[3 * 64 * LDAP];   // ~51 KB (gemm) / reused by hist
    const int t = threadIdx.x;

    if (blockIdx.x >= GB) {
        // ---- sort_hist (frozen r6+ body) ----
        int* bh = (int*)smem;
        const int b = blockIdx.x - GB;
        for (int i = t; i < BUCKETS; i += 256) bh[i] = 0;
        __syncthreads();
        const int base = b * CHUNK;
        const int end = (base + CHUNK < E_EDGES) ? base + CHUNK : E_EDGES;
        for (int i = base + t; i < end; i += 256)
            atomicAdd(&bh[dst[i] >> 8], 1);
        __syncthreads();
        for (int i = t; i < BUCKETS; i += 256)
            counts[i * NBLK + b] = bh[i];
        return;
    }

    // ---- MFMA gemm (r9 body, flat smem) ----
    ushort* hs  = smem;
    ushort* wfs = smem + 64 * LDAP;
    ushort* wrs = smem + 2 * 64 * LDAP;

    const int nb0 = blockIdx.x * 64;
    const int lane = t & 63;
    const int lr   = lane & 15;
    const int lq   = lane >> 4;

    // inline probe: C/D mapping (exact bf16/fp32 values, proven r4-r9)
    int flagv;
    {
        bf16x8 af = {0,0,0,0,0,0,0,0};
        bf16x8 bf = {0,0,0,0,0,0,0,0};
        if (lane < 16) {
            af[0] = (short)f2bf((float)(1 + lane));
            bf[0] = (short)f2bf((float)((1 + lane) * (1 + lane)));
        }
        f32x4 pacc = {0.f, 0.f, 0.f, 0.f};
        pacc = __builtin_amdgcn_mfma_f32_16x16x32_bf16(af, bf, pacc, 0, 0, 0);
        bool ok0 = true, ok1 = true;
        #pragma unroll
        for (int r = 0; r < 4; ++r) {
            float e0 = (float)((1 + lq * 4 + r) * (1 + lr) * (1 + lr));
            float e1 = (float)((1 + lr) * (1 + lq * 4 + r) * (1 + lq * 4 + r));
            ok0 = ok0 && (pacc[r] == e0);
            ok1 = ok1 && (pacc[r] == e1);
        }
        flagv = __all(ok0 ? 1 : 0) ? 0 : (__all(ok1 ? 1 : 0) ? 1 : 4);
    }

    #pragma unroll
    for (int i = 0; i < 8; ++i) {
        int elem = i * 1024 + t * 4;
        int row = elem >> 7, col = elem & 127;
        int hn = nb0 + row; if (hn >= N_NODES) hn = N_NODES - 1;
        float4 hv = *(const float4*)&h  [(size_t)hn  * IN_DIM + col];
        float4 fv = *(const float4*)&Wf [(size_t)row * IN_DIM + col];
        float4 rv = *(const float4*)&Wfr[(size_t)row * IN_DIM + col];
        ushort4 hu = { f2bf(hv.x), f2bf(hv.y), f2bf(hv.z), f2bf(hv.w) };
        ushort4 fu = { f2bf(fv.x), f2bf(fv.y), f2bf(fv.z), f2bf(fv.w) };
        ushort4 ru = { f2bf(rv.x), f2bf(rv.y), f2bf(rv.z), f2bf(rv.w) };
        *(ushort4*)&hs [row * LDAP + col] = hu;
        *(ushort4*)&wfs[row * LDAP + col] = fu;
        *(ushort4*)&wrs[row * LDAP + col] = ru;
    }
    __syncthreads();

    if (flagv >= 2) {
        // ---- inline VALU fallback from staged bf16 LDS (self-healing) ----
        const int og = t & 15;
        const int ng = t >> 4;
        #pragma unroll
        for (int i = 0; i < 4; ++i) {
            const int nrow = ng * 4 + i;
            const int node = nb0 + nrow;
            if (node >= N_NODES) continue;
            float acf[4] = {0.f, 0.f, 0.f, 0.f};
            float acr[4] = {0.f, 0.f, 0.f, 0.f};
            for (int k = 0; k < IN_DIM; ++k) {
                float hv = bf2f(hs[nrow * LDAP + k]);
                #pragma unroll
                for (int jj = 0; jj < 4; ++jj) {
                    acf[jj] = fmaf(hv, bf2f(wfs[(og * 4 + jj) * LDAP + k]), acf[jj]);
                    acr[jj] = fmaf(hv, bf2f(wrs[(og * 4 + jj) * LDAP + k]), acr[jj]);
                }
            }
            #pragma unroll
            for (int jj = 0; jj < 4; ++jj) {
                z [(size_t)node * OUT_DIM + og * 4 + jj] = f2bf(acf[jj]);
                zr[(size_t)node * OUT_DIM + og * 4 + jj] = f2bf(acr[jj]);
            }
        }
        return;
    }

    const int w = t >> 6;

    f32x4 accf[4], accr[4];
    #pragma unroll
    for (int cb = 0; cb < 4; ++cb) {
        accf[cb] = (f32x4){0.f, 0.f, 0.f, 0.f};
        accr[cb] = (f32x4){0.f, 0.f, 0.f, 0.f};
    }

    #pragma unroll
    for (int kc = 0; kc < 4; ++kc) {
        const int koff = kc * 32 + lq * 8;
        bf16x8 af = *(bf16x8*)&hs[(w * 16 + lr) * LDAP + koff];
        #pragma unroll
        for (int cb = 0; cb < 4; ++cb) {
            bf16x8 bfr = *(bf16x8*)&wfs[(cb * 16 + lr) * LDAP + koff];
            bf16x8 brr = *(bf16x8*)&wrs[(cb * 16 + lr) * LDAP + koff];
            accf[cb] = __builtin_amdgcn_mfma_f32_16x16x32_bf16(af, bfr, accf[cb], 0, 0, 0);
            accr[cb] = __builtin_amdgcn_mfma_f32_16x16x32_bf16(af, brr, accr[cb], 0, 0, 0);
        }
    }

    #pragma unroll
    for (int reg = 0; reg < 4; ++reg) {
        const int aIdx = (flagv == 0) ? (lq * 4 + reg) : lr;
        const int bIdx = (flagv == 0) ? lr : (lq * 4 + reg);
        const int node = nb0 + w * 16 + aIdx;
        if (node < N_NODES) {
            #pragma unroll
            for (int cb = 0; cb < 4; ++cb) {
                z [(size_t)node * OUT_DIM + cb * 16 + bIdx] = f2bf(accf[cb][reg]);
                zr[(size_t)node * OUT_DIM + cb * 16 + bIdx] = f2bf(accr[cb][reg]);
            }
        }
    }
}

// ============================================================
// k2: blocks [0,A4B) = a4; blocks [A4B, A4B+BUCKETS) = sort_scanA.
// ============================================================
__global__ __launch_bounds__(256) void k2_a4_scanA(
    const ushort* __restrict__ z, const ushort* __restrict__ zr,
    const float* __restrict__ Wa, float4* __restrict__ a4,
    const int* __restrict__ counts, int* __restrict__ scanw,
    int* __restrict__ btot)
{
    __shared__ int tmp[256];
    const int t = threadIdx.x;

    if (blockIdx.x >= A4B) {
        // ---- sort_scanA (frozen r7+ body) ----
        const int j = blockIdx.x - A4B;
        int v = (t < NBLK) ? counts[j * NBLK + t] : 0;
        tmp[t] = v; __syncthreads();
        #pragma unroll
        for (int off = 1; off < 256; off <<= 1) {
            int u = (t >= off) ? tmp[t - off] : 0;
            __syncthreads();
            tmp[t] += u;
            __syncthreads();
        }
        if (t < NBLK) scanw[j * NBLK + t] = tmp[t] - v;
        if (t == 255) btot[j] = tmp[t];
        return;
    }

    // ---- a4 (frozen r4+ body) ----
    int gid = blockIdx.x * 256 + t;
    int node = gid >> 4;
    int lr = t & 15;
    if (node >= N_NODES) return;
    ushort4 zv = *(const ushort4*)&z [(size_t)node * OUT_DIM + lr * 4];
    ushort4 rv = *(const ushort4*)&zr[(size_t)node * OUT_DIM + lr * 4];
    float4 ws4 = *(const float4*)&Wa[lr * 4];
    float4 wd4 = *(const float4*)&Wa[64 + lr * 4];
    float pSf = bf2f(zv.x)*ws4.x + bf2f(zv.y)*ws4.y + bf2f(zv.z)*ws4.z + bf2f(zv.w)*ws4.w;
    float pDf = bf2f(zv.x)*wd4.x + bf2f(zv.y)*wd4.y + bf2f(zv.z)*wd4.z + bf2f(zv.w)*wd4.w;
    float pSr = bf2f(rv.x)*ws4.x + bf2f(rv.y)*ws4.y + bf2f(rv.z)*ws4.z + bf2f(rv.w)*ws4.w;
    float pDr = bf2f(rv.x)*wd4.x + bf2f(rv.y)*wd4.y + bf2f(rv.z)*wd4.z + bf2f(rv.w)*wd4.w;
    #pragma unroll
    for (int mm = 1; mm < 16; mm <<= 1) {
        pSf += __shfl_xor(pSf, mm, 64);
        pDf += __shfl_xor(pDf, mm, 64);
        pSr += __shfl_xor(pSr, mm, 64);
        pDr += __shfl_xor(pDr, mm, 64);
    }
    if (lr == 0) a4[node] = make_float4(pSf, pDf, pSr, pDr);
}

// ============================================================
// k3: scatter with LOCAL bucket-base scan
// ============================================================
__global__ __launch_bounds__(256) void k3_scatter(
    const int* __restrict__ src, const int* __restrict__ dst,
    const float2* __restrict__ dir, const int* __restrict__ scanw,
    const int* __restrict__ btot, int2* __restrict__ tmpbuf)
{
    __shared__ int2 recs[CHUNK];
    __shared__ int bh[BUCKETS];
    __shared__ int sc[256];
    __shared__ int cur[BUCKETS];
    __shared__ int exb[256];     // local exclusive bucket bases

    const int b = blockIdx.x;
    const int t = threadIdx.x;

    // local scan of btot -> exb (exclusive)
    {
        int v = (t < BUCKETS) ? btot[t] : 0;
        exb[t] = v; __syncthreads();
        #pragma unroll
        for (int off = 1; off < 256; off <<= 1) {
            int u = (t >= off) ? exb[t - off] : 0;
            __syncthreads();
            exb[t] += u;
            __syncthreads();
        }
        int ex = exb[t] - v;
        __syncthreads();
        exb[t] = ex;
    }

    const int base = b * CHUNK;
    const int end = (base + CHUNK < E_EDGES) ? base + CHUNK : E_EDGES;
    const int cnt = end - base;

    for (int i = t; i < BUCKETS; i += 256) bh[i] = 0;
    __syncthreads();

    for (int i = t; i < cnt; i += 256) {
        int e = base + i;
        int d = dst[e];
        float2 dd = dir[e];
        int pay = src[e] | ((dd.y != 0.f) ? 0x80000000 : 0);
        recs[i] = make_int2(pay, d);
        atomicAdd(&bh[d >> 8], 1);
    }
    __syncthreads();

    sc[t] = (t < BUCKETS) ? bh[t] : 0;
    __syncthreads();
    #pragma unroll
    for (int off = 1; off < 256; off <<= 1) {
        int v = (t >= off) ? sc[t - off] : 0;
        __syncthreads();
        sc[t] += v;
        __syncthreads();
    }
    if (t < BUCKETS) cur[t] = (t > 0) ? sc[t - 1] : 0;
    __syncthreads();

    for (int i = t; i < cnt; i += 256) {
        int2 r = recs[i];
        int bkt = r.y >> 8;
        int loc = atomicAdd(&cur[bkt], 1);
        int lbase = (bkt > 0) ? sc[bkt - 1] : 0;
        tmpbuf[scanw[bkt * NBLK + b] + exb[bkt] + (loc - lbase)] = r;
    }
}

// ============================================================
// k4: pass2 with LOCAL bucket-base scan; emits csr + start[]
// ============================================================
__global__ __launch_bounds__(256) void k4_pass2(
    const int* __restrict__ btot, const int2* __restrict__ tmpbuf,
    int* __restrict__ csr, int* __restrict__ start)
{
    __shared__ int nh[256];
    __shared__ int nex[256];
    __shared__ int ncur[256];
    __shared__ int stmp[256];
    __shared__ int2 recs[P2CAP];

    const int j = blockIdx.x;
    const int t = threadIdx.x;

    // local scan of btot -> exclusive base for bucket j
    int v = (t < BUCKETS) ? btot[t] : 0;
    stmp[t] = v; __syncthreads();
    #pragma unroll
    for (int off = 1; off < 256; off <<= 1) {
        int u = (t >= off) ? stmp[t - off] : 0;
        __syncthreads();
        stmp[t] += u;
        __syncthreads();
    }
    const int gbeg = stmp[j] - btot[j];     // exclusive base of bucket j
    const int cnt  = btot[j];
    const bool fits = (cnt <= P2CAP);

    nh[t] = 0;
    __syncthreads();

    for (int i = t; i < cnt; i += 256) {
        int2 r = tmpbuf[gbeg + i];
        if (fits) recs[i] = r;
        atomicAdd(&nh[r.y & 255], 1);
    }
    __syncthreads();

    nex[t] = nh[t];
    __syncthreads();
    #pragma unroll
    for (int off = 1; off < 256; off <<= 1) {
        int u = (t >= off) ? nex[t - off] : 0;
        __syncthreads();
        nex[t] += u;
        __syncthreads();
    }
    int excl = (t > 0) ? nex[t - 1] : 0;
    ncur[t] = excl;
    const int node = j * 256 + t;
    if (node < N_NODES) start[node] = gbeg + excl;
    if (j == BUCKETS - 1 && t == 0) start[N_NODES] = E_EDGES;
    __syncthreads();

    for (int i = t; i < cnt; i += 256) {
        int2 r = fits ? recs[i] : tmpbuf[gbeg + i];
        int lid = r.y & 255;
        int loc = atomicAdd(&ncur[lid], 1);
        csr[gbeg + loc] = r.x;
    }
}

// ============================================================
// k5: fused softmax+aggregate (frozen r9 body: no-max softmax)
// ============================================================
__global__ __launch_bounds__(256) void k5_aggregate(
    const int* __restrict__ start, const int* __restrict__ csr,
    const float4* __restrict__ a4, const ushort* __restrict__ z,
    const ushort* __restrict__ zr, float* __restrict__ out)
{
    int gid = blockIdx.x * 256 + threadIdx.x;
    int node = gid >> 6;
    int lane = threadIdx.x & 63;
    int l = lane & 15;
    int g = lane >> 4;
    if (node >= N_NODES) return;

    const int s0 = start[node];
    const int s1 = start[node + 1];
    const float4 an = a4[node];

    float ssum = 0.f;
    float ax = 0.f, ay = 0.f, az = 0.f, aw = 0.f;

    for (int base = s0; base < s1; base += 64) {
        int k = base + lane;
        int p = 0;
        float wv = 0.f;
        if (k < s1) {
            p = csr[k];
            int sd = p & 0x7FFFFFFF;
            float4 a = a4[sd];
            float tl = (p < 0) ? (a.z + an.w) : (a.x + an.y);
            tl = (tl > 0.f) ? tl : NEG_SLOPE * tl;
            wv = __expf(tl);
        }
        float ws = wv;
        #pragma unroll
        for (int off = 1; off < 64; off <<= 1) ws += __shfl_xor(ws, off, 64);
        ssum += ws;

        int cnt = s1 - base; if (cnt > 64) cnt = 64;
        for (int j = 0; j < cnt; j += 4) {
            int jj = j + g;
            float wj = __shfl(wv, jj, 64);
            int   pj = __shfl(p,  jj, 64);
            if (jj < cnt) {
                int sdj = pj & 0x7FFFFFFF;
                const ushort* __restrict__ row = (pj < 0) ? zr : z;
                ushort4 v = *(const ushort4*)&row[(size_t)sdj * OUT_DIM + l * 4];
                ax = fmaf(wj, bf2f(v.x), ax);
                ay = fmaf(wj, bf2f(v.y), ay);
                az = fmaf(wj, bf2f(v.z), az);
                aw = fmaf(wj, bf2f(v.w), aw);
            }
        }
    }

    ax += __shfl_xor(ax, 16, 64); ax += __shfl_xor(ax, 32, 64);
    ay += __shfl_xor(ay, 16, 64); ay += __shfl_xor(ay, 32, 64);
    az += __shfl_xor(az, 16, 64); az += __shfl_xor(az, 32, 64);
    aw += __shfl_xor(aw, 16, 64); aw += __shfl_xor(aw, 32, 64);

    float inv = 1.f / fmaxf(ssum, 1e-9f);
    if (g == 0)
        *(float4*)&out[(size_t)node * OUT_DIM + l * 4] =
            make_float4(ax * inv, ay * inv, az * inv, aw * inv);
}

extern "C" void kernel_launch(void* const* d_in, const int* in_sizes, int n_in,
                              void* d_out, int out_size, void* d_ws, size_t ws_size,
                              hipStream_t stream) {
    const float*  h   = (const float*) d_in[0];
    const float*  Wf  = (const float*) d_in[1];
    const float*  Wfr = (const float*) d_in[2];
    const float*  Wa  = (const float*) d_in[3];
    const float2* dir = (const float2*)d_in[4];
    const int*    src = (const int*)   d_in[5];
    const int*    dst = (const int*)   d_in[6];
    float* out = (float*)d_out;

    // ws (4B words): zb zrb | a4 | counts scanw btot start | tmp csr
    ushort*   zb     = (ushort*)d_ws;
    ushort*   zrb    = zb + (size_t)N_NODES * OUT_DIM;
    float4*   a4     = (float4*)(zrb + (size_t)N_NODES * OUT_DIM);
    int*      counts = (int*)(a4 + N_NODES);
    int*      scanw  = counts + 38656;
    int*      btot   = scanw + 38656;
    int*      start  = btot + 256;
    int2*     tmp    = (int2*)(start + 50016);
    int*      csr    = (int*)(tmp + E_EDGES);

    k1_gemm_hist <<<GB + NBLK, 256, 0, stream>>>(h, Wf, Wfr, dst, zb, zrb, counts);
    k2_a4_scanA  <<<A4B + BUCKETS, 256, 0, stream>>>(zb, zrb, Wa, a4, counts, scanw, btot);
    k3_scatter   <<<NBLK, 256, 0, stream>>>(src, dst, dir, scanw, btot, tmp);
    k4_pass2     <<<BUCKETS, 256, 0, stream>>>(btot, tmp, csr, start);
    k5_aggregate <<<(N_NODES * 64 + 255) / 256, 256, 0, stream>>>(start, csr, a4, zb, zrb, out);
}

// Round 14
// 79.874 us; speedup vs baseline: 1.1938x; 1.0292x over previous
//
#include <hip/hip_runtime.h>

#define N_NODES 50000
#define E_EDGES 800000
#define IN_DIM  128
#define OUT_DIM 64
#define NEG_SLOPE 0.01f
#define LDAP 136                            // padded bf16 row stride

#define BUCKETS 196                         // ceil(N/256): bucket = dst>>8
#define NBLK    196                         // sort blocks
#define CHUNK   4096                        // edges per sort block
#define P2CAP   6144
#define GB      ((N_NODES + 63) / 64)       // 782 gemm blocks
#define A4B     ((N_NODES * 16 + 255) / 256)// 3125 a4 blocks

typedef __attribute__((ext_vector_type(8))) short bf16x8;
typedef __attribute__((ext_vector_type(4))) float f32x4;

__device__ __forceinline__ ushort f2bf(float x) {
    unsigned u = __float_as_uint(x);
    return (ushort)((u + 0x7FFFu + ((u >> 16) & 1u)) >> 16);
}
__device__ __forceinline__ float bf2f(ushort u) {
    return __uint_as_float(((unsigned)u) << 16);
}

// ============================================================
// k1: blocks [0,GB) = MFMA gemm (inline probe + inline VALU fallback);
//     blocks [GB, GB+NBLK) = sort_hist.   (frozen r10 body)
// ============================================================
__global__ __launch_bounds__(256) void k1_gemm_hist(
    const float* __restrict__ h, const float* __restrict__ Wf,
    const float* __restrict__ Wfr, const int* __restrict__ dst,
    ushort* __restrict__ z, ushort* __restrict__ zr, int* __restrict__ counts)
{
    __shared__ ushort smem[3 * 64 * LDAP];
    const int t = threadIdx.x;

    if (blockIdx.x >= GB) {
        int* bh = (int*)smem;
        const int b = blockIdx.x - GB;
        for (int i = t; i < BUCKETS; i += 256) bh[i] = 0;
        __syncthreads();
        const int base = b * CHUNK;
        const int end = (base + CHUNK < E_EDGES) ? base + CHUNK : E_EDGES;
        for (int i = base + t; i < end; i += 256)
            atomicAdd(&bh[dst[i] >> 8], 1);
        __syncthreads();
        for (int i = t; i < BUCKETS; i += 256)
            counts[i * NBLK + b] = bh[i];
        return;
    }

    ushort* hs  = smem;
    ushort* wfs = smem + 64 * LDAP;
    ushort* wrs = smem + 2 * 64 * LDAP;

    const int nb0 = blockIdx.x * 64;
    const int lane = t & 63;
    const int lr   = lane & 15;
    const int lq   = lane >> 4;

    int flagv;
    {
        bf16x8 af = {0,0,0,0,0,0,0,0};
        bf16x8 bf = {0,0,0,0,0,0,0,0};
        if (lane < 16) {
            af[0] = (short)f2bf((float)(1 + lane));
            bf[0] = (short)f2bf((float)((1 + lane) * (1 + lane)));
        }
        f32x4 pacc = {0.f, 0.f, 0.f, 0.f};
        pacc = __builtin_amdgcn_mfma_f32_16x16x32_bf16(af, bf, pacc, 0, 0, 0);
        bool ok0 = true, ok1 = true;
        #pragma unroll
        for (int r = 0; r < 4; ++r) {
            float e0 = (float)((1 + lq * 4 + r) * (1 + lr) * (1 + lr));
            float e1 = (float)((1 + lr) * (1 + lq * 4 + r) * (1 + lq * 4 + r));
            ok0 = ok0 && (pacc[r] == e0);
            ok1 = ok1 && (pacc[r] == e1);
        }
        flagv = __all(ok0 ? 1 : 0) ? 0 : (__all(ok1 ? 1 : 0) ? 1 : 4);
    }

    #pragma unroll
    for (int i = 0; i < 8; ++i) {
        int elem = i * 1024 + t * 4;
        int row = elem >> 7, col = elem & 127;
        int hn = nb0 + row; if (hn >= N_NODES) hn = N_NODES - 1;
        float4 hv = *(const float4*)&h  [(size_t)hn  * IN_DIM + col];
        float4 fv = *(const float4*)&Wf [(size_t)row * IN_DIM + col];
        float4 rv = *(const float4*)&Wfr[(size_t)row * IN_DIM + col];
        ushort4 hu = { f2bf(hv.x), f2bf(hv.y), f2bf(hv.z), f2bf(hv.w) };
        ushort4 fu = { f2bf(fv.x), f2bf(fv.y), f2bf(fv.z), f2bf(fv.w) };
        ushort4 ru = { f2bf(rv.x), f2bf(rv.y), f2bf(rv.z), f2bf(rv.w) };
        *(ushort4*)&hs [row * LDAP + col] = hu;
        *(ushort4*)&wfs[row * LDAP + col] = fu;
        *(ushort4*)&wrs[row * LDAP + col] = ru;
    }
    __syncthreads();

    if (flagv >= 2) {
        const int og = t & 15;
        const int ng = t >> 4;
        #pragma unroll
        for (int i = 0; i < 4; ++i) {
            const int nrow = ng * 4 + i;
            const int node = nb0 + nrow;
            if (node >= N_NODES) continue;
            float acf[4] = {0.f, 0.f, 0.f, 0.f};
            float acr[4] = {0.f, 0.f, 0.f, 0.f};
            for (int k = 0; k < IN_DIM; ++k) {
                float hv = bf2f(hs[nrow * LDAP + k]);
                #pragma unroll
                for (int jj = 0; jj < 4; ++jj) {
                    acf[jj] = fmaf(hv, bf2f(wfs[(og * 4 + jj) * LDAP + k]), acf[jj]);
                    acr[jj] = fmaf(hv, bf2f(wrs[(og * 4 + jj) * LDAP + k]), acr[jj]);
                }
            }
            #pragma unroll
            for (int jj = 0; jj < 4; ++jj) {
                z [(size_t)node * OUT_DIM + og * 4 + jj] = f2bf(acf[jj]);
                zr[(size_t)node * OUT_DIM + og * 4 + jj] = f2bf(acr[jj]);
            }
        }
        return;
    }

    const int w = t >> 6;

    f32x4 accf[4], accr[4];
    #pragma unroll
    for (int cb = 0; cb < 4; ++cb) {
        accf[cb] = (f32x4){0.f, 0.f, 0.f, 0.f};
        accr[cb] = (f32x4){0.f, 0.f, 0.f, 0.f};
    }

    #pragma unroll
    for (int kc = 0; kc < 4; ++kc) {
        const int koff = kc * 32 + lq * 8;
        bf16x8 af = *(bf16x8*)&hs[(w * 16 + lr) * LDAP + koff];
        #pragma unroll
        for (int cb = 0; cb < 4; ++cb) {
            bf16x8 bfr = *(bf16x8*)&wfs[(cb * 16 + lr) * LDAP + koff];
            bf16x8 brr = *(bf16x8*)&wrs[(cb * 16 + lr) * LDAP + koff];
            accf[cb] = __builtin_amdgcn_mfma_f32_16x16x32_bf16(af, bfr, accf[cb], 0, 0, 0);
            accr[cb] = __builtin_amdgcn_mfma_f32_16x16x32_bf16(af, brr, accr[cb], 0, 0, 0);
        }
    }

    #pragma unroll
    for (int reg = 0; reg < 4; ++reg) {
        const int aIdx = (flagv == 0) ? (lq * 4 + reg) : lr;
        const int bIdx = (flagv == 0) ? lr : (lq * 4 + reg);
        const int node = nb0 + w * 16 + aIdx;
        if (node < N_NODES) {
            #pragma unroll
            for (int cb = 0; cb < 4; ++cb) {
                z [(size_t)node * OUT_DIM + cb * 16 + bIdx] = f2bf(accf[cb][reg]);
                zr[(size_t)node * OUT_DIM + cb * 16 + bIdx] = f2bf(accr[cb][reg]);
            }
        }
    }
}

// ============================================================
// k2: blocks [0,A4B) = a4; blocks [A4B, A4B+BUCKETS) = sort_scanA. (frozen)
// ============================================================
__global__ __launch_bounds__(256) void k2_a4_scanA(
    const ushort* __restrict__ z, const ushort* __restrict__ zr,
    const float* __restrict__ Wa, float4* __restrict__ a4,
    const int* __restrict__ counts, int* __restrict__ scanw,
    int* __restrict__ btot)
{
    __shared__ int tmp[256];
    const int t = threadIdx.x;

    if (blockIdx.x >= A4B) {
        const int j = blockIdx.x - A4B;
        int v = (t < NBLK) ? counts[j * NBLK + t] : 0;
        tmp[t] = v; __syncthreads();
        #pragma unroll
        for (int off = 1; off < 256; off <<= 1) {
            int u = (t >= off) ? tmp[t - off] : 0;
            __syncthreads();
            tmp[t] += u;
            __syncthreads();
        }
        if (t < NBLK) scanw[j * NBLK + t] = tmp[t] - v;
        if (t == 255) btot[j] = tmp[t];
        return;
    }

    int gid = blockIdx.x * 256 + t;
    int node = gid >> 4;
    int lr = t & 15;
    if (node >= N_NODES) return;
    ushort4 zv = *(const ushort4*)&z [(size_t)node * OUT_DIM + lr * 4];
    ushort4 rv = *(const ushort4*)&zr[(size_t)node * OUT_DIM + lr * 4];
    float4 ws4 = *(const float4*)&Wa[lr * 4];
    float4 wd4 = *(const float4*)&Wa[64 + lr * 4];
    float pSf = bf2f(zv.x)*ws4.x + bf2f(zv.y)*ws4.y + bf2f(zv.z)*ws4.z + bf2f(zv.w)*ws4.w;
    float pDf = bf2f(zv.x)*wd4.x + bf2f(zv.y)*wd4.y + bf2f(zv.z)*wd4.z + bf2f(zv.w)*wd4.w;
    float pSr = bf2f(rv.x)*ws4.x + bf2f(rv.y)*ws4.y + bf2f(rv.z)*ws4.z + bf2f(rv.w)*ws4.w;
    float pDr = bf2f(rv.x)*wd4.x + bf2f(rv.y)*wd4.y + bf2f(rv.z)*wd4.z + bf2f(rv.w)*wd4.w;
    #pragma unroll
    for (int mm = 1; mm < 16; mm <<= 1) {
        pSf += __shfl_xor(pSf, mm, 64);
        pDf += __shfl_xor(pDf, mm, 64);
        pSr += __shfl_xor(pSr, mm, 64);
        pDr += __shfl_xor(pDr, mm, 64);
    }
    if (lr == 0) a4[node] = make_float4(pSf, pDf, pSr, pDr);
}

// ============================================================
// k3: scatter with LOCAL bucket-base scan (frozen r10 body)
// ============================================================
__global__ __launch_bounds__(256) void k3_scatter(
    const int* __restrict__ src, const int* __restrict__ dst,
    const float2* __restrict__ dir, const int* __restrict__ scanw,
    const int* __restrict__ btot, int2* __restrict__ tmpbuf)
{
    __shared__ int2 recs[CHUNK];
    __shared__ int bh[BUCKETS];
    __shared__ int sc[256];
    __shared__ int cur[BUCKETS];
    __shared__ int exb[256];

    const int b = blockIdx.x;
    const int t = threadIdx.x;

    {
        int v = (t < BUCKETS) ? btot[t] : 0;
        exb[t] = v; __syncthreads();
        #pragma unroll
        for (int off = 1; off < 256; off <<= 1) {
            int u = (t >= off) ? exb[t - off] : 0;
            __syncthreads();
            exb[t] += u;
            __syncthreads();
        }
        int ex = exb[t] - v;
        __syncthreads();
        exb[t] = ex;
    }

    const int base = b * CHUNK;
    const int end = (base + CHUNK < E_EDGES) ? base + CHUNK : E_EDGES;
    const int cnt = end - base;

    for (int i = t; i < BUCKETS; i += 256) bh[i] = 0;
    __syncthreads();

    for (int i = t; i < cnt; i += 256) {
        int e = base + i;
        int d = dst[e];
        float2 dd = dir[e];
        int pay = src[e] | ((dd.y != 0.f) ? 0x80000000 : 0);
        recs[i] = make_int2(pay, d);
        atomicAdd(&bh[d >> 8], 1);
    }
    __syncthreads();

    sc[t] = (t < BUCKETS) ? bh[t] : 0;
    __syncthreads();
    #pragma unroll
    for (int off = 1; off < 256; off <<= 1) {
        int v = (t >= off) ? sc[t - off] : 0;
        __syncthreads();
        sc[t] += v;
        __syncthreads();
    }
    if (t < BUCKETS) cur[t] = (t > 0) ? sc[t - 1] : 0;
    __syncthreads();

    for (int i = t; i < cnt; i += 256) {
        int2 r = recs[i];
        int bkt = r.y >> 8;
        int loc = atomicAdd(&cur[bkt], 1);
        int lbase = (bkt > 0) ? sc[bkt - 1] : 0;
        tmpbuf[scanw[bkt * NBLK + b] + exb[bkt] + (loc - lbase)] = r;
    }
}

// ============================================================
// k4: pass2 with LOCAL bucket-base scan; emits csr + start[] (frozen)
// ============================================================
__global__ __launch_bounds__(256) void k4_pass2(
    const int* __restrict__ btot, const int2* __restrict__ tmpbuf,
    int* __restrict__ csr, int* __restrict__ start)
{
    __shared__ int nh[256];
    __shared__ int nex[256];
    __shared__ int ncur[256];
    __shared__ int stmp[256];
    __shared__ int2 recs[P2CAP];

    const int j = blockIdx.x;
    const int t = threadIdx.x;

    int v = (t < BUCKETS) ? btot[t] : 0;
    stmp[t] = v; __syncthreads();
    #pragma unroll
    for (int off = 1; off < 256; off <<= 1) {
        int u = (t >= off) ? stmp[t - off] : 0;
        __syncthreads();
        stmp[t] += u;
        __syncthreads();
    }
    const int gbeg = stmp[j] - btot[j];
    const int cnt  = btot[j];
    const bool fits = (cnt <= P2CAP);

    nh[t] = 0;
    __syncthreads();

    for (int i = t; i < cnt; i += 256) {
        int2 r = tmpbuf[gbeg + i];
        if (fits) recs[i] = r;
        atomicAdd(&nh[r.y & 255], 1);
    }
    __syncthreads();

    nex[t] = nh[t];
    __syncthreads();
    #pragma unroll
    for (int off = 1; off < 256; off <<= 1) {
        int u = (t >= off) ? nex[t - off] : 0;
        __syncthreads();
        nex[t] += u;
        __syncthreads();
    }
    int excl = (t > 0) ? nex[t - 1] : 0;
    ncur[t] = excl;
    const int node = j * 256 + t;
    if (node < N_NODES) start[node] = gbeg + excl;
    if (j == BUCKETS - 1 && t == 0) start[N_NODES] = E_EDGES;
    __syncthreads();

    for (int i = t; i < cnt; i += 256) {
        int2 r = fits ? recs[i] : tmpbuf[gbeg + i];
        int lid = r.y & 255;
        int loc = atomicAdd(&ncur[lid], 1);
        csr[gbeg + loc] = r.x;
    }
}

// ============================================================
// k5: fused softmax+aggregate. Phase 1 frozen (no-max softmax, scalar a4
// load). Phase 2: 8 edge slots x 8 lanes (2x MLP vs r10's 4x16).
// ============================================================
__global__ __launch_bounds__(256) void k5_aggregate(
    const int* __restrict__ start, const int* __restrict__ csr,
    const float4* __restrict__ a4, const ushort* __restrict__ z,
    const ushort* __restrict__ zr, float* __restrict__ out)
{
    int gid = blockIdx.x * 256 + threadIdx.x;
    int node = gid >> 6;
    int lane = threadIdx.x & 63;
    int l = lane & 7;       // channel octet: cols l*8..l*8+7
    int g = lane >> 3;      // edge slot 0..7
    if (node >= N_NODES) return;

    const int s0 = start[node];
    const int s1 = start[node + 1];
    const float4 an = a4[node];
    const float* __restrict__ a4f = (const float*)a4;

    float ssum = 0.f;
    float a0 = 0.f, a1 = 0.f, a2 = 0.f, a3 = 0.f;
    float a4_ = 0.f, a5 = 0.f, a6 = 0.f, a7 = 0.f;

    for (int base = s0; base < s1; base += 64) {
        // ---- phase 1: per-lane logit -> w (scalar a4 gather: 4B) ----
        int k = base + lane;
        int p = 0;
        float wv = 0.f;
        if (k < s1) {
            p = csr[k];
            int sd = p & 0x7FFFFFFF;
            float tl = (p < 0) ? (a4f[(size_t)sd * 4 + 2] + an.w)
                               : (a4f[(size_t)sd * 4 + 0] + an.y);
            tl = (tl > 0.f) ? tl : NEG_SLOPE * tl;
            wv = __expf(tl);                 // |logit| <~ 20 -> fp32-safe
        }
        float ws = wv;
        #pragma unroll
        for (int off = 1; off < 64; off <<= 1) ws += __shfl_xor(ws, off, 64);
        ssum += ws;

        // ---- phase 2: 8 edges/iter; 8-lane group g handles edge j+g ----
        int cnt = s1 - base; if (cnt > 64) cnt = 64;
        for (int j = 0; j < cnt; j += 8) {
            int jj = j + g;                  // <= 63 always (j <= 56)
            float wj = __shfl(wv, jj, 64);
            int   pj = __shfl(p,  jj, 64);
            if (jj < cnt) {
                int sdj = pj & 0x7FFFFFFF;
                const ushort* __restrict__ row = (pj < 0) ? zr : z;
                ushort4 v0 = *(const ushort4*)&row[(size_t)sdj * OUT_DIM + l * 8];
                ushort4 v1 = *(const ushort4*)&row[(size_t)sdj * OUT_DIM + l * 8 + 4];
                a0 = fmaf(wj, bf2f(v0.x), a0);
                a1 = fmaf(wj, bf2f(v0.y), a1);
                a2 = fmaf(wj, bf2f(v0.z), a2);
                a3 = fmaf(wj, bf2f(v0.w), a3);
                a4_ = fmaf(wj, bf2f(v1.x), a4_);
                a5 = fmaf(wj, bf2f(v1.y), a5);
                a6 = fmaf(wj, bf2f(v1.z), a6);
                a7 = fmaf(wj, bf2f(v1.w), a7);
            }
        }
    }

    // reduce partials across the 8 edge-slot groups (lane bits 3,4,5)
    #pragma unroll
    for (int off = 8; off < 64; off <<= 1) {
        a0 += __shfl_xor(a0, off, 64);
        a1 += __shfl_xor(a1, off, 64);
        a2 += __shfl_xor(a2, off, 64);
        a3 += __shfl_xor(a3, off, 64);
        a4_ += __shfl_xor(a4_, off, 64);
        a5 += __shfl_xor(a5, off, 64);
        a6 += __shfl_xor(a6, off, 64);
        a7 += __shfl_xor(a7, off, 64);
    }

    if (g == 0) {
        float inv = 1.f / fmaxf(ssum, 1e-9f);
        *(float4*)&out[(size_t)node * OUT_DIM + l * 8] =
            make_float4(a0 * inv, a1 * inv, a2 * inv, a3 * inv);
        *(float4*)&out[(size_t)node * OUT_DIM + l * 8 + 4] =
            make_float4(a4_ * inv, a5 * inv, a6 * inv, a7 * inv);
    }
}

extern "C" void kernel_launch(void* const* d_in, const int* in_sizes, int n_in,
                              void* d_out, int out_size, void* d_ws, size_t ws_size,
                              hipStream_t stream) {
    const float*  h   = (const float*) d_in[0];
    const float*  Wf  = (const float*) d_in[1];
    const float*  Wfr = (const float*) d_in[2];
    const float*  Wa  = (const float*) d_in[3];
    const float2* dir = (const float2*)d_in[4];
    const int*    src = (const int*)   d_in[5];
    const int*    dst = (const int*)   d_in[6];
    float* out = (float*)d_out;

    // ws (4B words): zb zrb | a4 | counts scanw btot start | tmp csr
    ushort*   zb     = (ushort*)d_ws;
    ushort*   zrb    = zb + (size_t)N_NODES * OUT_DIM;
    float4*   a4     = (float4*)(zrb + (size_t)N_NODES * OUT_DIM);
    int*      counts = (int*)(a4 + N_NODES);
    int*      scanw  = counts + 38656;
    int*      btot   = scanw + 38656;
    int*      start  = btot + 256;
    int2*     tmp    = (int2*)(start + 50016);
    int*      csr    = (int*)(tmp + E_EDGES);

    k1_gemm_hist <<<GB + NBLK, 256, 0, stream>>>(h, Wf, Wfr, dst, zb, zrb, counts);
    k2_a4_scanA  <<<A4B + BUCKETS, 256, 0, stream>>>(zb, zrb, Wa, a4, counts, scanw, btot);
    k3_scatter   <<<NBLK, 256, 0, stream>>>(src, dst, dir, scanw, btot, tmp);
    k4_pass2     <<<BUCKETS, 256, 0, stream>>>(btot, tmp, csr, start);
    k5_aggregate <<<(N_NODES * 64 + 255) / 256, 256, 0, stream>>>(start, csr, a4, zb, zrb, out);
}